// Round 1
// baseline (331.919 us; speedup 1.0000x reference)
//
#include <hip/hip_runtime.h>
#include <hip/hip_bf16.h>

#define T_LEN 4096
#define EMB   1024
#define NHEADS 8
#define HDIM  128
#define NPROJ 1280   // 1024 (Q) + 128 (K) + 128 (V)

typedef __attribute__((ext_vector_type(8))) short bf16x8;
typedef __attribute__((ext_vector_type(4))) short s16x4;
typedef __attribute__((ext_vector_type(4))) float f32x4;

__device__ __forceinline__ short f2bf(float f) {
    unsigned u = __builtin_bit_cast(unsigned, f);
    u += 0x7fffu + ((u >> 16) & 1u);   // RNE
    return (short)(u >> 16);
}

// ---------------- PE table: pe[t][2i]=sin(t*f_i), pe[t][2i+1]=cos(t*f_i) ----------------
__global__ void pe_kernel(float* __restrict__ pe) {
    int idx = blockIdx.x * 256 + threadIdx.x;           // 4096*64 pairs
    if (idx >= T_LEN * 64) return;
    int t = idx >> 6, i = idx & 63;
    float f = expf(-9.210340371976184f * (float)i / 64.0f);
    float a = (float)t * f;
    pe[t * HDIM + 2 * i]     = sinf(a);
    pe[t * HDIM + 2 * i + 1] = cosf(a);
}

// ---------------- f32 -> bf16 convert (4 elems/thread), strided dst ----------------
__global__ void cvt_kernel(const float* __restrict__ src, short* __restrict__ dst,
                           int rows, int cols, int dstride) {
    int vi = blockIdx.x * 256 + threadIdx.x;
    int e0 = vi * 4;
    if (e0 >= rows * cols) return;
    int r = e0 / cols, c = e0 - r * cols;
    f32x4 v = *(const f32x4*)(src + e0);
    s16x4 o;
    for (int j = 0; j < 4; ++j) o[j] = f2bf(v[j]);
    *(s16x4*)(dst + (long)r * dstride + c) = o;
}

// ---------------- bf16 MFMA GEMM, 64x64 tile, 4 waves (2x2), BK=32 ----------------
// MODE 0: proj  C = x@[Wq|Wkv], epilogue: +bias +pe, split-store Q/K/Vt (bf16)
// MODE 1: out   C = attn@Wo -> fp32 d_out
template<int MODE>
__global__ __launch_bounds__(256)
void gemm_kernel(const short* __restrict__ A, const short* __restrict__ B,
                 const float* __restrict__ bq, const float* __restrict__ bkv,
                 const float* __restrict__ pe,
                 short* __restrict__ Qb, short* __restrict__ Kb, short* __restrict__ Vtb,
                 float* __restrict__ Cout, int N, int K) {
    const int tid = threadIdx.x;
    const int lane = tid & 63;
    const int wid  = tid >> 6;
    const int m0 = blockIdx.x * 64, n0 = blockIdx.y * 64;
    const int wr = (wid >> 1) * 32, wc = (wid & 1) * 32;
    const int l15 = lane & 15, lk = lane >> 4;

    // stride 40 shorts (80B): 16B-aligned rows, 2-way-max bank aliasing (free)
    __shared__ short As[64 * 40];
    __shared__ short Bts[64 * 40];   // B tile transposed: Bts[n][k]

    f32x4 acc[2][2] = {};

    for (int k0 = 0; k0 < K; k0 += 32) {
        {   // stage A: 64x32, one 16B chunk per thread
            int row = tid >> 2, c8 = (tid & 3) * 8;
            bf16x8 v = *(const bf16x8*)(A + (long)(m0 + row) * K + k0 + c8);
            *(bf16x8*)(As + row * 40 + c8) = v;
        }
        {   // stage B transposed: read 8 consecutive n, scatter to Bts[n][k]
            int kk = tid >> 3, n8 = (tid & 7) * 8;
            bf16x8 v = *(const bf16x8*)(B + (long)(k0 + kk) * N + n0 + n8);
            for (int j = 0; j < 8; ++j) Bts[(n8 + j) * 40 + kk] = v[j];
        }
        __syncthreads();
        bf16x8 a0 = *(const bf16x8*)(As + (wr + l15) * 40 + lk * 8);
        bf16x8 a1 = *(const bf16x8*)(As + (wr + 16 + l15) * 40 + lk * 8);
        bf16x8 b0 = *(const bf16x8*)(Bts + (wc + l15) * 40 + lk * 8);
        bf16x8 b1 = *(const bf16x8*)(Bts + (wc + 16 + l15) * 40 + lk * 8);
        acc[0][0] = __builtin_amdgcn_mfma_f32_16x16x32_bf16(a0, b0, acc[0][0], 0, 0, 0);
        acc[0][1] = __builtin_amdgcn_mfma_f32_16x16x32_bf16(a0, b1, acc[0][1], 0, 0, 0);
        acc[1][0] = __builtin_amdgcn_mfma_f32_16x16x32_bf16(a1, b0, acc[1][0], 0, 0, 0);
        acc[1][1] = __builtin_amdgcn_mfma_f32_16x16x32_bf16(a1, b1, acc[1][1], 0, 0, 0);
        __syncthreads();
    }

    // epilogue; C/D layout: col = lane&15, row = (lane>>4)*4 + r   [m89-verified]
    for (int mi = 0; mi < 2; ++mi)
        for (int ni = 0; ni < 2; ++ni)
            for (int r = 0; r < 4; ++r) {
                int row = m0 + wr + mi * 16 + lk * 4 + r;
                int col = n0 + wc + ni * 16 + l15;
                float v = acc[mi][ni][r];
                if (MODE == 0) {
                    if (col < 1024) {            // Q: +bq +pe, per-head layout row x 1024
                        v += bq[col] + pe[row * HDIM + (col & 127)];
                        Qb[(long)row * 1024 + col] = f2bf(v);
                    } else if (col < 1152) {     // K: +bkv[0:128] +pe
                        int d = col - 1024;
                        v += bkv[d] + pe[row * HDIM + d];
                        Kb[row * HDIM + d] = f2bf(v);
                    } else {                     // V: +bkv[128:256], store transposed [d][t]
                        v += bkv[col - 1024];
                        Vtb[(long)(col - 1152) * T_LEN + row] = f2bf(v);
                    }
                } else {
                    Cout[(long)row * 1024 + col] = v;
                }
            }
}

// ---------------- flash attention: 4 waves x 16 q-rows, KVBLK=64, fp32 online softmax ----------------
__global__ __launch_bounds__(256)
void attn_kernel(const short* __restrict__ Qb, const short* __restrict__ Kb,
                 const short* __restrict__ Vtb, short* __restrict__ Ob) {
    const int tid = threadIdx.x, lane = tid & 63, w = tid >> 6;
    const int qb = blockIdx.x * 64, h = blockIdx.y;
    const int qw = qb + w * 16;
    const int l15 = lane & 15, lk = lane >> 4;

    // XOR-swizzled LDS (G4: row-major D=128 tiles = heavy bank conflicts; ^((row&7)<<4) -> ~2-way)
    __shared__ __align__(16) char Ks[64 * 256];    // K tile  [key][d]  bf16
    __shared__ __align__(16) char Vts[128 * 128];  // V^T tile [d][key] bf16
    __shared__ __align__(16) char Ps[4 * 2048];    // per-wave P [16][64] bf16

    // Q fragments in registers: row = lane&15, k = (lane>>4)*8+j  (A-operand layout)
    bf16x8 qa[4];
    for (int kc = 0; kc < 4; ++kc)
        qa[kc] = *(const bf16x8*)(Qb + (long)(qw + l15) * 1024 + h * HDIM + kc * 32 + lk * 8);

    f32x4 o[8] = {};
    float m[4] = {-INFINITY, -INFINITY, -INFINITY, -INFINITY};
    float l[4] = {0.f, 0.f, 0.f, 0.f};

    const int nkt = blockIdx.x + 1;
    for (int kt = 0; kt < nkt; ++kt) {
        const int kbase = kt * 64;
        __syncthreads();
        for (int c = 0; c < 4; ++c) {
            int chunk = c * 256 + tid;
            {   // K tile: 64 x 128 bf16
                int row = chunk >> 4, c8 = (chunk & 15) * 8;
                bf16x8 v = *(const bf16x8*)(Kb + (long)(kbase + row) * HDIM + c8);
                *(bf16x8*)(Ks + ((row * 256 + c8 * 2) ^ ((row & 7) << 4))) = v;
            }
            {   // V^T tile: 128 x 64 bf16
                int d = chunk >> 3, k8 = (chunk & 7) * 8;
                bf16x8 v = *(const bf16x8*)(Vtb + (long)d * T_LEN + kbase + k8);
                *(bf16x8*)(Vts + ((d * 128 + k8 * 2) ^ ((d & 7) << 4))) = v;
            }
        }
        __syncthreads();

        // S = q @ K^T  (4 column tiles of 16 keys, K-dim = 128 = 4 chunks)
        f32x4 S[4];
        for (int ct = 0; ct < 4; ++ct) {
            f32x4 s = {};
            for (int kc = 0; kc < 4; ++kc) {
                int row = ct * 16 + l15;
                bf16x8 b = *(const bf16x8*)(Ks + ((row * 256 + (kc * 32 + lk * 8) * 2) ^ ((row & 7) << 4)));
                s = __builtin_amdgcn_mfma_f32_16x16x32_bf16(qa[kc], b, s, 0, 0, 0);
            }
            s *= 0.08838834764831845f;   // 1/sqrt(128)
            if (kt == nkt - 1) {         // causal mask: only diagonal 64-block needs it
                int key = kbase + ct * 16 + l15;
                for (int r = 0; r < 4; ++r) {
                    int query = qw + lk * 4 + r;
                    if (key > query) s[r] = -1e30f;
                }
            }
            S[ct] = s;
        }

        // online softmax per query row r (rows = lk*4+r, cols across 16 lanes)
        float sc[4];
        for (int r = 0; r < 4; ++r) {
            float tm = fmaxf(fmaxf(S[0][r], S[1][r]), fmaxf(S[2][r], S[3][r]));
            for (int off = 1; off < 16; off <<= 1) tm = fmaxf(tm, __shfl_xor(tm, off));
            float nm = fmaxf(m[r], tm);
            sc[r] = expf(m[r] - nm);
            m[r] = nm;
            float ps = 0.f;
            int prow = lk * 4 + r;
            for (int ct = 0; ct < 4; ++ct) {
                float p = expf(S[ct][r] - nm);
                ps += p;
                *(short*)(Ps + w * 2048 + ((prow * 128 + (ct * 16 + l15) * 2) ^ ((prow & 7) << 4))) = f2bf(p);
            }
            for (int off = 1; off < 16; off <<= 1) ps += __shfl_xor(ps, off);
            l[r] = l[r] * sc[r] + ps;
        }
        for (int dt = 0; dt < 8; ++dt)
            for (int r = 0; r < 4; ++r) o[dt][r] *= sc[r];

        // O += P @ V   (A = P from LDS, B = V^T tile read contiguously)
        bf16x8 pa[2];
        for (int kc = 0; kc < 2; ++kc)
            pa[kc] = *(const bf16x8*)(Ps + w * 2048 + ((l15 * 128 + (kc * 32 + lk * 8) * 2) ^ ((l15 & 7) << 4)));
        for (int dt = 0; dt < 8; ++dt) {
            int vrow = dt * 16 + l15;
            for (int kc = 0; kc < 2; ++kc) {
                bf16x8 vb = *(const bf16x8*)(Vts + ((vrow * 128 + (kc * 32 + lk * 8) * 2) ^ ((vrow & 7) << 4)));
                o[dt] = __builtin_amdgcn_mfma_f32_16x16x32_bf16(pa[kc], vb, o[dt], 0, 0, 0);
            }
        }
    }

    // epilogue: attn (bf16) row-major [T][H*D]
    for (int dt = 0; dt < 8; ++dt)
        for (int r = 0; r < 4; ++r) {
            int row = qw + lk * 4 + r;
            int col = h * HDIM + dt * 16 + l15;
            Ob[(long)row * 1024 + col] = f2bf(o[dt][r] / l[r]);
        }
}

extern "C" void kernel_launch(void* const* d_in, const int* in_sizes, int n_in,
                              void* d_out, int out_size, void* d_ws, size_t ws_size,
                              hipStream_t stream) {
    const float* x   = (const float*)d_in[0];
    const float* Wq  = (const float*)d_in[1];
    const float* bq  = (const float*)d_in[2];
    const float* Wkv = (const float*)d_in[3];
    const float* bkv = (const float*)d_in[4];
    const float* Wo  = (const float*)d_in[5];
    float* out = (float*)d_out;
    char* ws = (char*)d_ws;

    float* pe  = (float*)(ws);                        // 4096*128*4  = 2 MiB
    short* xb  = (short*)(ws + (2l  << 20));          // 4096*1024*2 = 8 MiB
    short* wb  = (short*)(ws + (10l << 20));          // 1024*1280*2 = 2.5 MiB
    short* wob = (short*)(ws + (13l << 20));          // 1024*1024*2 = 2 MiB
    short* Qb  = (short*)(ws + (15l << 20));          // 4096*1024*2 = 8 MiB
    short* Kb  = (short*)(ws + (23l << 20));          // 4096*128*2  = 1 MiB
    short* Vtb = (short*)(ws + (24l << 20));          // 128*4096*2  = 1 MiB
    short* Ab  = (short*)(ws + (25l << 20));          // 4096*1024*2 = 8 MiB

    pe_kernel<<<1024, 256, 0, stream>>>(pe);
    cvt_kernel<<<4096, 256, 0, stream>>>(x,   xb,  T_LEN, EMB, EMB);
    cvt_kernel<<<1024, 256, 0, stream>>>(Wq,  wb,  EMB, 1024, NPROJ);
    cvt_kernel<<<256,  256, 0, stream>>>(Wkv, wb + 1024, EMB, 256, NPROJ);
    cvt_kernel<<<1024, 256, 0, stream>>>(Wo,  wob, EMB, 1024, 1024);

    gemm_kernel<0><<<dim3(64, 20), 256, 0, stream>>>(xb, wb, bq, bkv, pe,
                                                     Qb, Kb, Vtb, nullptr, NPROJ, EMB);
    attn_kernel<<<dim3(64, 8), 256, 0, stream>>>(Qb, Kb, Vtb, Ab);
    gemm_kernel<1><<<dim3(64, 16), 256, 0, stream>>>(Ab, wob, nullptr, nullptr, nullptr,
                                                     nullptr, nullptr, nullptr, out, 1024, EMB);
}

// Round 2
// 242.234 us; speedup vs baseline: 1.3702x; 1.3702x over previous
//
#include <hip/hip_runtime.h>
#include <hip/hip_bf16.h>

#define T_LEN 4096
#define EMB   1024
#define NHEADS 8
#define HDIM  128
#define NPROJ 1280   // 1024 (Q) + 128 (K) + 128 (V)
#define QSCALE 0.12752039955379307f   // (1/sqrt(128)) * log2(e) -- folded into Q

typedef __attribute__((ext_vector_type(8))) short bf16x8;
typedef __attribute__((ext_vector_type(4))) short s16x4;
typedef __attribute__((ext_vector_type(4))) float f32x4;

__device__ __forceinline__ short f2bf(float f) {
    unsigned u = __builtin_bit_cast(unsigned, f);
    u += 0x7fffu + ((u >> 16) & 1u);   // RNE
    return (short)(u >> 16);
}

__device__ __forceinline__ unsigned cvt_pk_bf16(float lo, float hi) {
    unsigned r;
    asm("v_cvt_pk_bf16_f32 %0, %1, %2" : "=v"(r) : "v"(lo), "v"(hi));
    return r;
}

// ---------------- PE table: pe[t][2i]=sin(t*f_i), pe[t][2i+1]=cos(t*f_i) ----------------
__global__ void pe_kernel(float* __restrict__ pe) {
    int idx = blockIdx.x * 256 + threadIdx.x;           // 4096*64 pairs
    if (idx >= T_LEN * 64) return;
    int t = idx >> 6, i = idx & 63;
    float f = expf(-9.210340371976184f * (float)i / 64.0f);
    float a = (float)t * f;
    pe[t * HDIM + 2 * i]     = sinf(a);
    pe[t * HDIM + 2 * i + 1] = cosf(a);
}

// ---------------- f32 -> bf16 convert (4 elems/thread), strided dst ----------------
__global__ void cvt_kernel(const float* __restrict__ src, short* __restrict__ dst,
                           int rows, int cols, int dstride) {
    int vi = blockIdx.x * 256 + threadIdx.x;
    int e0 = vi * 4;
    if (e0 >= rows * cols) return;
    int r = e0 / cols, c = e0 - r * cols;
    f32x4 v = *(const f32x4*)(src + e0);
    s16x4 o;
    for (int j = 0; j < 4; ++j) o[j] = f2bf(v[j]);
    *(s16x4*)(dst + (long)r * dstride + c) = o;
}

// ---------------- bf16 MFMA GEMM, 64x64 tile, 4 waves (2x2), BK=32 ----------------
// MODE 0: proj  C = x@[Wq|Wkv], epilogue: +bias +pe (Q also *QSCALE), split-store Q/K/Vt
// MODE 1: out   C = attn@Wo -> fp32 d_out
template<int MODE>
__global__ __launch_bounds__(256)
void gemm_kernel(const short* __restrict__ A, const short* __restrict__ B,
                 const float* __restrict__ bq, const float* __restrict__ bkv,
                 const float* __restrict__ pe,
                 short* __restrict__ Qb, short* __restrict__ Kb, short* __restrict__ Vtb,
                 float* __restrict__ Cout, int N, int K) {
    const int tid = threadIdx.x;
    const int lane = tid & 63;
    const int wid  = tid >> 6;
    const int m0 = blockIdx.x * 64, n0 = blockIdx.y * 64;
    const int wr = (wid >> 1) * 32, wc = (wid & 1) * 32;
    const int l15 = lane & 15, lk = lane >> 4;

    __shared__ short As[64 * 40];
    __shared__ short Bts[64 * 40];   // B tile transposed: Bts[n][k]

    f32x4 acc[2][2] = {};

    for (int k0 = 0; k0 < K; k0 += 32) {
        {   // stage A: 64x32, one 16B chunk per thread
            int row = tid >> 2, c8 = (tid & 3) * 8;
            bf16x8 v = *(const bf16x8*)(A + (long)(m0 + row) * K + k0 + c8);
            *(bf16x8*)(As + row * 40 + c8) = v;
        }
        {   // stage B transposed
            int kk = tid >> 3, n8 = (tid & 7) * 8;
            bf16x8 v = *(const bf16x8*)(B + (long)(k0 + kk) * N + n0 + n8);
            for (int j = 0; j < 8; ++j) Bts[(n8 + j) * 40 + kk] = v[j];
        }
        __syncthreads();
        bf16x8 a0 = *(const bf16x8*)(As + (wr + l15) * 40 + lk * 8);
        bf16x8 a1 = *(const bf16x8*)(As + (wr + 16 + l15) * 40 + lk * 8);
        bf16x8 b0 = *(const bf16x8*)(Bts + (wc + l15) * 40 + lk * 8);
        bf16x8 b1 = *(const bf16x8*)(Bts + (wc + 16 + l15) * 40 + lk * 8);
        acc[0][0] = __builtin_amdgcn_mfma_f32_16x16x32_bf16(a0, b0, acc[0][0], 0, 0, 0);
        acc[0][1] = __builtin_amdgcn_mfma_f32_16x16x32_bf16(a0, b1, acc[0][1], 0, 0, 0);
        acc[1][0] = __builtin_amdgcn_mfma_f32_16x16x32_bf16(a1, b0, acc[1][0], 0, 0, 0);
        acc[1][1] = __builtin_amdgcn_mfma_f32_16x16x32_bf16(a1, b1, acc[1][1], 0, 0, 0);
        __syncthreads();
    }

    // epilogue; C/D layout: col = lane&15, row = (lane>>4)*4 + r
    for (int mi = 0; mi < 2; ++mi)
        for (int ni = 0; ni < 2; ++ni)
            for (int r = 0; r < 4; ++r) {
                int row = m0 + wr + mi * 16 + lk * 4 + r;
                int col = n0 + wc + ni * 16 + l15;
                float v = acc[mi][ni][r];
                if (MODE == 0) {
                    if (col < 1024) {            // Q: (+bq +pe) * QSCALE (base-2 softmax domain)
                        v = (v + bq[col] + pe[row * HDIM + (col & 127)]) * QSCALE;
                        Qb[(long)row * 1024 + col] = f2bf(v);
                    } else if (col < 1152) {     // K: +bkv[0:128] +pe
                        int d = col - 1024;
                        v += bkv[d] + pe[row * HDIM + d];
                        Kb[row * HDIM + d] = f2bf(v);
                    } else {                     // V: +bkv[128:256], store transposed [d][t]
                        v += bkv[col - 1024];
                        Vtb[(long)(col - 1152) * T_LEN + row] = f2bf(v);
                    }
                } else {
                    Cout[(long)row * 1024 + col] = v;
                }
            }
}

// ---------------- flash attention v2 ----------------
// Swapped QK^T (S^T = mfma(K,Q)) -> lane-local softmax; exp2 domain (scale folded into Q);
// double-buffered K/V LDS with async-stage split (issue loads early, ds_write late);
// one barrier per KV tile; setprio around MFMA clusters.
__global__ __launch_bounds__(256, 2)
void attn_kernel(const short* __restrict__ Qb, const short* __restrict__ Kb,
                 const short* __restrict__ Vtb, short* __restrict__ Ob) {
    const int tid = threadIdx.x, lane = tid & 63, w = tid >> 6;
    const int l15 = lane & 15, lk = lane >> 4;
    const int i = blockIdx.x >> 3, h = blockIdx.x & 7;
    // near-equal-length pairing: blocks bx and bx+256 (co-resident on a CU) get qt pair (2k+1, 2k)
    const int qt = (i < 32) ? (63 - 2 * i) : (62 - 2 * (i - 32));
    const int qw = qt * 64 + w * 16;
    const int nkt = qt + 1;

    __shared__ __align__(16) char Ks[2][64 * 256];    // K tile  [key][d]  bf16, XOR-swizzled
    __shared__ __align__(16) char Vts[2][128 * 128];  // V^T tile [d][key] bf16, XOR-swizzled
    __shared__ __align__(16) char Ps[4][2048];        // per-wave P [16 q][64 k] bf16, XOR-swizzled

    // Q fragments (B-operand layout: lane l15 = query col, k = lk*8+j). Pre-scaled by QSCALE.
    bf16x8 qa[4];
#pragma unroll
    for (int kc = 0; kc < 4; ++kc)
        qa[kc] = *(const bf16x8*)(Qb + (long)(qw + l15) * 1024 + h * HDIM + kc * 32 + lk * 8);

    f32x4 o[8] = {};
    float m2 = -INFINITY, lsum = 0.f;   // per-lane scalars: lane owns query l15

    bf16x8 kreg[4], vreg[4];
    {   // prologue: stage tile 0
#pragma unroll
        for (int c = 0; c < 4; ++c) {
            int chunk = c * 256 + tid;
            int row = chunk >> 4, c8 = (chunk & 15) * 8;
            kreg[c] = *(const bf16x8*)(Kb + (long)row * HDIM + c8);
            int d = chunk >> 3, k8 = (chunk & 7) * 8;
            vreg[c] = *(const bf16x8*)(Vtb + (long)d * T_LEN + k8);
        }
#pragma unroll
        for (int c = 0; c < 4; ++c) {
            int chunk = c * 256 + tid;
            int row = chunk >> 4, c8 = (chunk & 15) * 8;
            *(bf16x8*)(Ks[0] + ((row * 256 + c8 * 2) ^ ((row & 7) << 4))) = kreg[c];
            int d = chunk >> 3, k8 = (chunk & 7) * 8;
            *(bf16x8*)(Vts[0] + ((d * 128 + k8 * 2) ^ ((d & 7) << 4))) = vreg[c];
        }
    }
    __syncthreads();

    for (int kt = 0; kt < nkt; ++kt) {
        const int cur = kt & 1;
        const bool pf = (kt + 1 < nkt);

        if (pf) {   // T14: issue next-tile global loads now; ds_write after compute
            const int kbase = (kt + 1) * 64;
#pragma unroll
            for (int c = 0; c < 4; ++c) {
                int chunk = c * 256 + tid;
                int row = chunk >> 4, c8 = (chunk & 15) * 8;
                kreg[c] = *(const bf16x8*)(Kb + (long)(kbase + row) * HDIM + c8);
                int d = chunk >> 3, k8 = (chunk & 7) * 8;
                vreg[c] = *(const bf16x8*)(Vtb + (long)d * T_LEN + kbase + k8);
            }
        }

        // S^T = K @ Q^T : D[key_local][query], col = l15 = query, row = lk*4+r = key_local
        f32x4 S[4];
        __builtin_amdgcn_s_setprio(1);
#pragma unroll
        for (int ct = 0; ct < 4; ++ct) {
            f32x4 s = {};
#pragma unroll
            for (int kc = 0; kc < 4; ++kc) {
                int row = ct * 16 + l15;
                bf16x8 a = *(const bf16x8*)(Ks[cur] + ((row * 256 + (kc * 32 + lk * 8) * 2) ^ ((row & 7) << 4)));
                s = __builtin_amdgcn_mfma_f32_16x16x32_bf16(a, qa[kc], s, 0, 0, 0);
            }
            S[ct] = s;
        }
        __builtin_amdgcn_s_setprio(0);

        if (kt == nkt - 1) {   // causal mask: only the diagonal tile
            const int query = qw + l15;
#pragma unroll
            for (int ct = 0; ct < 4; ++ct)
#pragma unroll
                for (int r = 0; r < 4; ++r)
                    if (kt * 64 + ct * 16 + lk * 4 + r > query) S[ct][r] = -1e30f;
        }

        // lane-local softmax (base-2); only 2+2 shfl_xor across the 4 lanes sharing query l15
        f32x4 mx4;
#pragma unroll
        for (int j = 0; j < 4; ++j)
            mx4[j] = fmaxf(fmaxf(S[0][j], S[1][j]), fmaxf(S[2][j], S[3][j]));
        float tm = fmaxf(fmaxf(mx4[0], mx4[1]), fmaxf(mx4[2], mx4[3]));
        tm = fmaxf(tm, __shfl_xor(tm, 16));
        tm = fmaxf(tm, __shfl_xor(tm, 32));
        float nm = fmaxf(m2, tm);
        float sc = __builtin_amdgcn_exp2f(m2 - nm);
        m2 = nm;
        f32x4 ps4 = {};
#pragma unroll
        for (int ct = 0; ct < 4; ++ct) {
#pragma unroll
            for (int j = 0; j < 4; ++j)
                S[ct][j] = __builtin_amdgcn_exp2f(S[ct][j] - nm);
            ps4 += S[ct];
        }
        float ps = (ps4[0] + ps4[1]) + (ps4[2] + ps4[3]);
        ps += __shfl_xor(ps, 16);
        ps += __shfl_xor(ps, 32);
        lsum = lsum * sc + ps;

        // P -> bf16 via cvt_pk, b64 stores into wave-private swizzled LDS
#pragma unroll
        for (int ct = 0; ct < 4; ++ct) {
            uint2 pk;
            pk.x = cvt_pk_bf16(S[ct][0], S[ct][1]);
            pk.y = cvt_pk_bf16(S[ct][2], S[ct][3]);
            *(uint2*)(Ps[w] + ((l15 * 128 + ct * 32 + lk * 8) ^ ((l15 & 7) << 4))) = pk;
        }

        // rescale O (rows = query lk*4+r): fetch per-row sc from owning lanes
        f32x4 scq;
#pragma unroll
        for (int r = 0; r < 4; ++r) scq[r] = __shfl(sc, lk * 4 + r);
#pragma unroll
        for (int dt = 0; dt < 8; ++dt) o[dt] *= scq;

        // O += P @ V  (A = P from LDS, B = V^T rows read contiguously)
        bf16x8 pa0 = *(const bf16x8*)(Ps[w] + ((l15 * 128 + lk * 16) ^ ((l15 & 7) << 4)));
        bf16x8 pa1 = *(const bf16x8*)(Ps[w] + ((l15 * 128 + 64 + lk * 16) ^ ((l15 & 7) << 4)));
        __builtin_amdgcn_s_setprio(1);
#pragma unroll
        for (int dt = 0; dt < 8; ++dt) {
            int vrow = dt * 16 + l15;
            bf16x8 vb0 = *(const bf16x8*)(Vts[cur] + ((vrow * 128 + lk * 16) ^ ((vrow & 7) << 4)));
            o[dt] = __builtin_amdgcn_mfma_f32_16x16x32_bf16(pa0, vb0, o[dt], 0, 0, 0);
            bf16x8 vb1 = *(const bf16x8*)(Vts[cur] + ((vrow * 128 + 64 + lk * 16) ^ ((vrow & 7) << 4)));
            o[dt] = __builtin_amdgcn_mfma_f32_16x16x32_bf16(pa1, vb1, o[dt], 0, 0, 0);
        }
        __builtin_amdgcn_s_setprio(0);

        if (pf) {   // write prefetched tile into the other buffer (readers of it synced last barrier)
            const int nb = cur ^ 1;
#pragma unroll
            for (int c = 0; c < 4; ++c) {
                int chunk = c * 256 + tid;
                int row = chunk >> 4, c8 = (chunk & 15) * 8;
                *(bf16x8*)(Ks[nb] + ((row * 256 + c8 * 2) ^ ((row & 7) << 4))) = kreg[c];
                int d = chunk >> 3, k8 = (chunk & 7) * 8;
                *(bf16x8*)(Vts[nb] + ((d * 128 + k8 * 2) ^ ((d & 7) << 4))) = vreg[c];
            }
        }
        __syncthreads();   // single barrier per tile
    }

    // epilogue: attn (bf16) row-major [T][H*D]
    f32x4 lq, rl;
#pragma unroll
    for (int r = 0; r < 4; ++r) lq[r] = __shfl(lsum, lk * 4 + r);
#pragma unroll
    for (int r = 0; r < 4; ++r) rl[r] = 1.0f / lq[r];
#pragma unroll
    for (int dt = 0; dt < 8; ++dt)
#pragma unroll
        for (int r = 0; r < 4; ++r) {
            int row = qw + lk * 4 + r;
            int col = h * HDIM + dt * 16 + l15;
            Ob[(long)row * 1024 + col] = f2bf(o[dt][r] * rl[r]);
        }
}

extern "C" void kernel_launch(void* const* d_in, const int* in_sizes, int n_in,
                              void* d_out, int out_size, void* d_ws, size_t ws_size,
                              hipStream_t stream) {
    const float* x   = (const float*)d_in[0];
    const float* Wq  = (const float*)d_in[1];
    const float* bq  = (const float*)d_in[2];
    const float* Wkv = (const float*)d_in[3];
    const float* bkv = (const float*)d_in[4];
    const float* Wo  = (const float*)d_in[5];
    float* out = (float*)d_out;
    char* ws = (char*)d_ws;

    float* pe  = (float*)(ws);                        // 4096*128*4  = 2 MiB
    short* xb  = (short*)(ws + (2l  << 20));          // 4096*1024*2 = 8 MiB
    short* wb  = (short*)(ws + (10l << 20));          // 1024*1280*2 = 2.5 MiB
    short* wob = (short*)(ws + (13l << 20));          // 1024*1024*2 = 2 MiB
    short* Qb  = (short*)(ws + (15l << 20));          // 4096*1024*2 = 8 MiB
    short* Kb  = (short*)(ws + (23l << 20));          // 4096*128*2  = 1 MiB
    short* Vtb = (short*)(ws + (24l << 20));          // 128*4096*2  = 1 MiB
    short* Ab  = (short*)(ws + (25l << 20));          // 4096*1024*2 = 8 MiB

    pe_kernel<<<1024, 256, 0, stream>>>(pe);
    cvt_kernel<<<4096, 256, 0, stream>>>(x,   xb,  T_LEN, EMB, EMB);
    cvt_kernel<<<1024, 256, 0, stream>>>(Wq,  wb,  EMB, 1024, NPROJ);
    cvt_kernel<<<256,  256, 0, stream>>>(Wkv, wb + 1024, EMB, 256, NPROJ);
    cvt_kernel<<<1024, 256, 0, stream>>>(Wo,  wob, EMB, 1024, 1024);

    gemm_kernel<0><<<dim3(64, 20), 256, 0, stream>>>(xb, wb, bq, bkv, pe,
                                                     Qb, Kb, Vtb, nullptr, NPROJ, EMB);
    attn_kernel<<<512, 256, 0, stream>>>(Qb, Kb, Vtb, Ab);
    gemm_kernel<1><<<dim3(64, 16), 256, 0, stream>>>(Ab, wob, nullptr, nullptr, nullptr,
                                                     nullptr, nullptr, nullptr, out, 1024, EMB);
}